// Round 3
// baseline (1034.163 us; speedup 1.0000x reference)
//
#include <hip/hip_runtime.h>

#define B_ 16
#define C_ 128
#define N_ 16384
#define TN 64
#define NTILES (B_ * (N_ / TN))  // 4096
#define NBLK 512
#define TPB (NTILES / NBLK)      // 8 tiles per block

typedef __attribute__((ext_vector_type(8))) short short8;
typedef __attribute__((ext_vector_type(4))) float f32x4;

__device__ inline unsigned short bf16_rn(float x) {
  unsigned u = __float_as_uint(x);
  unsigned r = u + 0x7FFFu + ((u >> 16) & 1u);
  return (unsigned short)(r >> 16);
}
__device__ inline float bf16_f(unsigned short h) {
  return __uint_as_float(((unsigned)h) << 16);
}

// wqsum[i] = sum_o Wq[o][i]
__global__ __launch_bounds__(128) void wq_colsum_kernel(const float* __restrict__ Wq,
                                                        float* __restrict__ wqsum) {
  int i = threadIdx.x;
  float s = 0.f;
#pragma unroll 8
  for (int o = 0; o < C_; ++o) s += Wq[o * C_ + i];
  wqsum[i] = s;
}

// Split Wk, Wv into bf16 hi/lo pairs: x ~= hi + lo, err ~2^-17.
__global__ __launch_bounds__(256) void w_convert_kernel(
    const float* __restrict__ Wk, const float* __restrict__ Wv,
    unsigned short* __restrict__ WkHi, unsigned short* __restrict__ WkLo,
    unsigned short* __restrict__ WvHi, unsigned short* __restrict__ WvLo) {
  int idx = blockIdx.x * 256 + threadIdx.x;  // 0..16383
  {
    float x = Wk[idx];
    unsigned short h = bf16_rn(x);
    WkHi[idx] = h;
    WkLo[idx] = bf16_rn(x - bf16_f(h));
  }
  {
    float x = Wv[idx];
    unsigned short h = bf16_rn(x);
    WvHi[idx] = h;
    WvLo[idx] = bf16_rn(x - bf16_f(h));
  }
}

// Persistent: 512 blocks x 512 threads, each block runs 8 column-tiles.
// 8 waves: wn = w>>1 picks 16-col group, wj = w&1 picks j-half [64*wj, 64*wj+64).
// LDS 48 KB (posHi/posLo/featHi) -> 2 blocks/CU -> 4 waves/SIMD.
// Next tile's fp32 inputs prefetched into registers to overlap HBM with compute.
__global__ __launch_bounds__(512, 4) void csa_mfma2_kernel(
    const float* __restrict__ feature, const float* __restrict__ position,
    const float* __restrict__ wqsum,
    const unsigned short* __restrict__ WkHi, const unsigned short* __restrict__ WkLo,
    const unsigned short* __restrict__ WvHi, const unsigned short* __restrict__ WvLo,
    float* __restrict__ out) {
  __shared__ unsigned short posHi[TN * 128];   // 16 KB, XOR-swizzled [n][i]
  __shared__ unsigned short posLo[TN * 128];   // 16 KB
  __shared__ unsigned short featHi[TN * 128];  // 16 KB
  __shared__ float redS[8][16], redMx[8][16], redMn[8][16], redE[8][16];

  const int tid = threadIdx.x;
  const int lane = tid & 63;
  const int w = tid >> 6;   // 0..7
  const int wn = w >> 1;    // col group 0..3
  const int wj = w & 1;     // j half
  const int m = lane & 15;
  const int q = lane >> 4;
  const int jbase = wj * 64;
  const int nloc = wn * 16 + m;
  const int fn8l = ((nloc & 15) ^ ((nloc >> 2) & 7)) * 8;
  const int rowb = nloc * 128;

  const int g32 = tid >> 4;       // 0..31 (row pair selector)
  const int n4 = (tid & 15) * 4;  // col group for staging

  float4 P[2][2], F[2][2];

  // ---- load tile 0 into registers ----
  {
    const int g0 = blockIdx.x * TPB;
    const float* pg = position + (size_t)(g0 >> 8) * C_ * N_ + (size_t)(g0 & 255) * TN;
    const float* fg = feature + (size_t)(g0 >> 8) * C_ * N_ + (size_t)(g0 & 255) * TN;
#pragma unroll
    for (int it = 0; it < 2; ++it) {
      int i = 64 * it + 2 * g32;
      P[it][0] = *(const float4*)(pg + (size_t)i * N_ + n4);
      P[it][1] = *(const float4*)(pg + (size_t)(i + 1) * N_ + n4);
      F[it][0] = *(const float4*)(fg + (size_t)i * N_ + n4);
      F[it][1] = *(const float4*)(fg + (size_t)(i + 1) * N_ + n4);
    }
  }

  for (int t = 0; t < TPB; ++t) {
    const int g = blockIdx.x * TPB + t;
    const int b = g >> 8;
    const int n0 = (g & 255) * TN;

    // ---- convert + write LDS (tile t) ----
#pragma unroll
    for (int it = 0; it < 2; ++it) {
      int i = 64 * it + 2 * g32;
      int c8 = (i >> 3) * 8;
      int ioff = i & 7;  // even
      const float* P0 = (const float*)&P[it][0];
      const float* P1 = (const float*)&P[it][1];
      const float* F0 = (const float*)&F[it][0];
      const float* F1 = (const float*)&F[it][1];
#pragma unroll
      for (int d = 0; d < 4; ++d) {
        int n = n4 + d;
        int fn8 = ((n & 15) ^ ((n >> 2) & 7)) * 8;
        int hw = n * 128 + (c8 ^ fn8) + ioff;
        unsigned short h0 = bf16_rn(P0[d]), h1 = bf16_rn(P1[d]);
        float l0 = P0[d] - bf16_f(h0);
        float l1 = P1[d] - bf16_f(h1);
        *(unsigned*)(posHi + hw) = (unsigned)h0 | ((unsigned)h1 << 16);
        *(unsigned*)(posLo + hw) = (unsigned)bf16_rn(l0) | ((unsigned)bf16_rn(l1) << 16);
        *(unsigned*)(featHi + hw) =
            (unsigned)bf16_rn(F0[d]) | ((unsigned)bf16_rn(F1[d]) << 16);
      }
    }
    __syncthreads();

    // ---- prefetch tile t+1 (overlaps the whole compute phase) ----
    if (t + 1 < TPB) {
      const int g2 = g + 1;
      const float* pg = position + (size_t)(g2 >> 8) * C_ * N_ + (size_t)(g2 & 255) * TN;
      const float* fg = feature + (size_t)(g2 >> 8) * C_ * N_ + (size_t)(g2 & 255) * TN;
#pragma unroll
      for (int it = 0; it < 2; ++it) {
        int i = 64 * it + 2 * g32;
        P[it][0] = *(const float4*)(pg + (size_t)i * N_ + n4);
        P[it][1] = *(const float4*)(pg + (size_t)(i + 1) * N_ + n4);
        F[it][0] = *(const float4*)(fg + (size_t)i * N_ + n4);
        F[it][1] = *(const float4*)(fg + (size_t)(i + 1) * N_ + n4);
      }
    }

    // ---- k-GEMM: k[j][nloc], j = jbase + jt*16 + q*4 + r ----
    f32x4 acck[4];
#pragma unroll
    for (int jt = 0; jt < 4; ++jt) acck[jt] = (f32x4){0.f, 0.f, 0.f, 0.f};
#pragma unroll
    for (int kk = 0; kk < 4; ++kk) {
      int bw = rowb + (((kk * 4 + q) * 8) ^ fn8l);
      short8 bHi = *(const short8*)(posHi + bw);
      short8 bLo = *(const short8*)(posLo + bw);
#pragma unroll
      for (int jt = 0; jt < 4; ++jt) {
        int woff = (jbase + jt * 16 + m) * 128 + kk * 32 + q * 8;
        short8 aHi = *(const short8*)(WkHi + woff);
        short8 aLo = *(const short8*)(WkLo + woff);
        acck[jt] = __builtin_amdgcn_mfma_f32_16x16x32_bf16(aHi, bHi, acck[jt], 0, 0, 0);
        acck[jt] = __builtin_amdgcn_mfma_f32_16x16x32_bf16(aHi, bLo, acck[jt], 0, 0, 0);
        acck[jt] = __builtin_amdgcn_mfma_f32_16x16x32_bf16(aLo, bHi, acck[jt], 0, 0, 0);
      }
    }

    // ---- sq = wqsum . pos[:, nloc] (quad q covers i in [32q,32q+32)) ----
    float sq = 0.f;
#pragma unroll
    for (int ii = 0; ii < 16; ++ii) {
      int i = q * 32 + 2 * ii;
      int hw = rowb + (((i >> 3) * 8) ^ fn8l) + (i & 7);
      unsigned hu = *(const unsigned*)(posHi + hw);
      unsigned lu = *(const unsigned*)(posLo + hw);
      float x0 = __uint_as_float(hu << 16) + __uint_as_float(lu << 16);
      float x1 = __uint_as_float(hu & 0xFFFF0000u) + __uint_as_float(lu & 0xFFFF0000u);
      float2 wq2 = *(const float2*)(wqsum + i);
      sq = fmaf(wq2.x, x0, fmaf(wq2.y, x1, sq));
    }
    sq += __shfl_xor(sq, 16, 64);
    sq += __shfl_xor(sq, 32, 64);

    // ---- softmax half-reductions + cross-wave exchange ----
    float ks = 0.f, kx = -__builtin_inff(), kn = __builtin_inff();
#pragma unroll
    for (int jt = 0; jt < 4; ++jt)
#pragma unroll
      for (int r = 0; r < 4; ++r) {
        ks += acck[jt][r];
        kx = fmaxf(kx, acck[jt][r]);
        kn = fminf(kn, acck[jt][r]);
      }
    ks += __shfl_xor(ks, 16, 64);
    ks += __shfl_xor(ks, 32, 64);
    kx = fmaxf(kx, __shfl_xor(kx, 16, 64));
    kx = fmaxf(kx, __shfl_xor(kx, 32, 64));
    kn = fminf(kn, __shfl_xor(kn, 16, 64));
    kn = fminf(kn, __shfl_xor(kn, 32, 64));
    if (q == 0) {
      redS[w][m] = ks;
      redMx[w][m] = kx;
      redMn[w][m] = kn;
    }
    __syncthreads();
    ks += redS[w ^ 1][m];
    kx = fmaxf(kx, redMx[w ^ 1][m]);
    kn = fminf(kn, redMn[w ^ 1][m]);

    float gg = sq / (1e-9f + sq * ks);
    float ml = (gg >= 0.f) ? gg * kx : gg * kn;

    float es = 0.f;
#pragma unroll
    for (int jt = 0; jt < 4; ++jt)
#pragma unroll
      for (int r = 0; r < 4; ++r) {
        float p = __expf(fmaf(gg, acck[jt][r], -ml));
        acck[jt][r] = p;
        es += p;
      }
    es += __shfl_xor(es, 16, 64);
    es += __shfl_xor(es, 32, 64);
    if (q == 0) redE[w][m] = es;
    __syncthreads();
    float inv = 1.0f / (es + redE[w ^ 1][m]);

    // ---- v-GEMM: (WvHi+WvLo) . featHi ----
    f32x4 accv[4];
#pragma unroll
    for (int jt = 0; jt < 4; ++jt) accv[jt] = (f32x4){0.f, 0.f, 0.f, 0.f};
#pragma unroll
    for (int kk = 0; kk < 4; ++kk) {
      int bw = rowb + (((kk * 4 + q) * 8) ^ fn8l);
      short8 bH = *(const short8*)(featHi + bw);
#pragma unroll
      for (int jt = 0; jt < 4; ++jt) {
        int woff = (jbase + jt * 16 + m) * 128 + kk * 32 + q * 8;
        short8 aHi = *(const short8*)(WvHi + woff);
        short8 aLo = *(const short8*)(WvLo + woff);
        accv[jt] = __builtin_amdgcn_mfma_f32_16x16x32_bf16(aHi, bH, accv[jt], 0, 0, 0);
        accv[jt] = __builtin_amdgcn_mfma_f32_16x16x32_bf16(aLo, bH, accv[jt], 0, 0, 0);
      }
    }
    __syncthreads();  // all LDS reads of tile t done; next iter may overwrite

    // ---- epilogue: out = att*v + feat (feat re-read fp32 from global, exact) ----
    const float* fb = feature + (size_t)b * C_ * N_ + n0 + nloc;
    float* ob = out + (size_t)b * C_ * N_ + n0 + nloc;
#pragma unroll
    for (int jt = 0; jt < 4; ++jt)
#pragma unroll
      for (int r = 0; r < 4; ++r) {
        int j = jbase + jt * 16 + q * 4 + r;
        ob[(size_t)j * N_] = fmaf(acck[jt][r] * inv, accv[jt][r], fb[(size_t)j * N_]);
      }
  }
}

extern "C" void kernel_launch(void* const* d_in, const int* in_sizes, int n_in,
                              void* d_out, int out_size, void* d_ws, size_t ws_size,
                              hipStream_t stream) {
  const float* feature = (const float*)d_in[0];
  const float* position = (const float*)d_in[1];
  const float* Wq = (const float*)d_in[2];
  const float* Wk = (const float*)d_in[3];
  const float* Wv = (const float*)d_in[4];
  float* out = (float*)d_out;

  char* ws = (char*)d_ws;
  float* wqsum = (float*)ws;                           // 512 B
  unsigned short* WkHi = (unsigned short*)(ws + 512);  // 32 KB each
  unsigned short* WkLo = (unsigned short*)(ws + 512 + 32768);
  unsigned short* WvHi = (unsigned short*)(ws + 512 + 65536);
  unsigned short* WvLo = (unsigned short*)(ws + 512 + 98304);

  wq_colsum_kernel<<<1, 128, 0, stream>>>(Wq, wqsum);
  w_convert_kernel<<<64, 256, 0, stream>>>(Wk, Wv, WkHi, WkLo, WvHi, WvLo);
  csa_mfma2_kernel<<<NBLK, 512, 0, stream>>>(feature, position, wqsum,
                                             WkHi, WkLo, WvHi, WvLo, out);
}